// Round 7
// baseline (88.829 us; speedup 1.0000x reference)
//
#include <hip/hip_runtime.h>

#define LOG2E 1.4426950408889634f
#define SCALE (2.0f * LOG2E)

__device__ __forceinline__ float fast_exp2(float x) { return __builtin_amdgcn_exp2f(x); }
__device__ __forceinline__ float fast_rcp(float x)  { return __builtin_amdgcn_rcpf(x); }

typedef __attribute__((ext_vector_type(8))) short bf16x8;
typedef __attribute__((ext_vector_type(4))) float f32x4;
typedef __attribute__((ext_vector_type(2))) float f32x2;
#define F2(u,v) ((f32x2){(u),(v)})

// ---------------- stage 0: pack A/B into bf16 hi/lo MFMA fragment panels ----------------
// Logical GEMM: C[m,n] = sum_{kp=0}^{1535} A[m,kp]*B[n,kp]
//   kp segment 0: x_hi*w_hi ; 1: x_lo*w_hi ; 2: x_hi*w_lo   (lo*lo dropped, ~1e-5 rel)
__global__ __launch_bounds__(256) void pack_kernel(const float* __restrict__ inputs,
                                                   const float* __restrict__ attn_W,
                                                   ushort* __restrict__ Ap,
                                                   ushort* __restrict__ Bp) {
    int tid = blockIdx.x * 256 + threadIdx.x;
    const bool isA = tid < 393216;
    int f = isA ? tid : tid - 393216;
    int l  = f & 63;
    int fr = (f >> 6) & 3;
    int ks = (f >> 8) & 1;
    int rem = f >> 9;
    int kt = rem % 24, tb = rem / 24;
    int kp = kt * 64 + ks * 32 + (l >> 4) * 8;
    int seg = kp >> 9, k = kp & 511;
    const float* src;
    bool useLo;
    if (isA) {
        int m = tb * 64 + fr * 16 + (l & 15);
        src = inputs + ((m & 255) * 8 + (m >> 8)) * 512 + k;
        useLo = (seg == 1);
    } else {
        int n = tb * 64 + fr * 16 + (l & 15);
        src = attn_W + (n & 511) * 1024 + (n >> 9) * 512 + k;
        useLo = (seg == 2);
    }
    float4 v0 = *(const float4*)src;
    float4 v1 = *(const float4*)(src + 4);
    float vv[8] = {v0.x, v0.y, v0.z, v0.w, v1.x, v1.y, v1.z, v1.w};
    ushort o[8];
#pragma unroll
    for (int j = 0; j < 8; ++j) {
        unsigned u = __float_as_uint(vv[j]);
        unsigned hi = (u + 0x7FFF + ((u >> 16) & 1)) >> 16;   // RN bf16
        if (useLo) {
            float lo = vv[j] - __uint_as_float(hi << 16);
            unsigned ul = __float_as_uint(lo);
            o[j] = (ushort)((ul + 0x7FFF + ((ul >> 16) & 1)) >> 16);
        } else {
            o[j] = (ushort)hi;
        }
    }
    ushort* dst = (isA ? Ap : Bp) + (long)f * 8;
    *(uint4*)dst = *(const uint4*)o;
}

// ---------------- stage 1: MFMA GEMM, tile 128x64, 4 waves 2x2, BK=64 dbuf ----------------
__global__ __launch_bounds__(256) void mfma_gemm(const ushort* __restrict__ Ap,
                                                 const ushort* __restrict__ Bp,
                                                 const float* __restrict__ attn_b,
                                                 float* __restrict__ E1,
                                                 float* __restrict__ E2) {
    const int mb = blockIdx.x & 15;
    const int nb = blockIdx.x >> 4;
    __shared__ ushort lds[2][12288];

    const int t = threadIdx.x;
    const int lane = t & 63, w = t >> 6;
    const int wr = w >> 1, wc = w & 1;

    const ushort* A0 = Ap + (long)(mb * 2 + 0) * 24 * 4096;
    const ushort* A1 = Ap + (long)(mb * 2 + 1) * 24 * 4096;
    const ushort* B0 = Bp + (long)nb * 24 * 4096;

    f32x4 acc[4][2];
#pragma unroll
    for (int i = 0; i < 4; ++i)
#pragma unroll
        for (int j = 0; j < 2; ++j)
            acc[i][j] = (f32x4){0.f, 0.f, 0.f, 0.f};

    uint4 st[6];
    st[0] = ((const uint4*)A0)[t];       st[1] = ((const uint4*)A0)[t + 256];
    st[2] = ((const uint4*)A1)[t];       st[3] = ((const uint4*)A1)[t + 256];
    st[4] = ((const uint4*)B0)[t];       st[5] = ((const uint4*)B0)[t + 256];
#pragma unroll
    for (int r = 0; r < 6; ++r) ((uint4*)lds[0])[t + r * 256] = st[r];
    __syncthreads();

    for (int kt = 0; kt < 24; ++kt) {
        if (kt < 23) {
            const uint4* a0 = (const uint4*)(A0 + (kt + 1) * 4096);
            const uint4* a1 = (const uint4*)(A1 + (kt + 1) * 4096);
            const uint4* b0 = (const uint4*)(B0 + (kt + 1) * 4096);
            st[0] = a0[t]; st[1] = a0[t + 256];
            st[2] = a1[t]; st[3] = a1[t + 256];
            st[4] = b0[t]; st[5] = b0[t + 256];
        }
        const ushort* buf = lds[kt & 1];
#pragma unroll
        for (int ks = 0; ks < 2; ++ks) {
            bf16x8 a[4], b[2];
#pragma unroll
            for (int mf = 0; mf < 4; ++mf)
                a[mf] = *(const bf16x8*)&buf[wr * 4096 + ks * 2048 + mf * 512 + lane * 8];
#pragma unroll
            for (int nn = 0; nn < 2; ++nn)
                b[nn] = *(const bf16x8*)&buf[8192 + ks * 2048 + (wc * 2 + nn) * 512 + lane * 8];
#pragma unroll
            for (int mf = 0; mf < 4; ++mf)
#pragma unroll
                for (int nn = 0; nn < 2; ++nn)
                    acc[mf][nn] = __builtin_amdgcn_mfma_f32_16x16x32_bf16(
                        a[mf], b[nn], acc[mf][nn], 0, 0, 0);
        }
        if (kt < 23) {
            ushort* nbuf = lds[(kt + 1) & 1];
#pragma unroll
            for (int r = 0; r < 6; ++r) ((uint4*)nbuf)[t + r * 256] = st[r];
            __syncthreads();
        }
    }

    const bool isE1 = (nb < 8);
    float* dst = isE1 ? E1 : E2;
    const int b = mb >> 1;
#pragma unroll
    for (int nn = 0; nn < 2; ++nn) {
        int n = nb * 64 + wc * 32 + nn * 16 + (lane & 15);
        int o = n & 511;
        float bias = isE1 ? attn_b[o] : 0.0f;
#pragma unroll
        for (int mf = 0; mf < 4; ++mf) {
            int ti = (mb & 1) * 4 + wr * 2 + (mf >> 1);
            int iibase = (mf & 1) * 16 + (lane >> 4) * 4;
            long rowoff = ((long)(b * 8 + ti) * 512 + o) * 32 + iibase;
#pragma unroll
            for (int r = 0; r < 4; ++r)
                dst[rowoff + r] = fast_exp2(SCALE * (acc[mf][nn][r] + bias));
        }
    }
}

// ---------------- stage 2: partial energies, 64x64 tile, 4x4/thread, 4-way rcp combine ----
// EP[s][b][i][j] = sum_{o in chunk s (64)} c_o * rcp(1 + E1[b,i,o]*E2[b,j,o])
// 4-way exact combine: sum_{q=0..3} c_q/y_q = n/d, y=1+x, d=y0y1y2y3,
//   n = (c0y1+c1y0)*y2y3 + (c2y3+c3y2)*y0y1
// Single LDS stage (As/Bs[64][65]), coalesced staging, bounded unroll.
__global__ __launch_bounds__(256) void energy_kernel(const float* __restrict__ E1,
                                                     const float* __restrict__ E2,
                                                     const float* __restrict__ sW,
                                                     float* __restrict__ EP) {
    const int bid = blockIdx.x;          // 1024 = s(8) b(8) ti(4) tj(4)
    const int tj = bid & 3;
    const int ti = (bid >> 2) & 3;
    const int b  = (bid >> 4) & 7;
    const int s  = bid >> 7;
    __shared__ float As[64 * 65];        // [i_local][o] pad 65 (~2-way banks max)
    __shared__ float Bs[64 * 65];        // [j_local][o]
    __shared__ float csh[64];

    const int t = threadIdx.x;
    const int tx = t & 15, ty = t >> 4;
    if (t < 64) csh[t] = 2.0f * sW[s * 64 + t];

    // staging: per tp, the (32 i x 64 o) slab is one contiguous 8KB chunk; flat = o*32+ii.
    {
        const int o0  = t >> 3;          // 0..31
        const int ii4 = (t & 7) * 4;     // lane-sequential: flat = 4*t  (coalesced)
#pragma unroll
        for (int tp = 0; tp < 2; ++tp) {
            const float* aC = E1 + ((long)(b * 8 + ti * 2 + tp) * 512 + s * 64) * 32;
            const float* bC = E2 + ((long)(b * 8 + tj * 2 + tp) * 512 + s * 64) * 32;
#pragma unroll
            for (int h = 0; h < 2; ++h) {
                const int o = o0 + h * 32;
                float4 va = *(const float4*)(aC + o * 32 + ii4);
                float4 vb = *(const float4*)(bC + o * 32 + ii4);
                const int rw = (tp * 32 + ii4) * 65 + o;
                As[rw]           = va.x;  As[rw + 65]      = va.y;
                As[rw + 130]     = va.z;  As[rw + 195]     = va.w;
                Bs[rw]           = vb.x;  Bs[rw + 65]      = vb.y;
                Bs[rw + 130]     = vb.z;  Bs[rw + 195]     = vb.w;
            }
        }
    }
    __syncthreads();

    f32x2 acc[4][2];
#pragma unroll
    for (int r = 0; r < 4; ++r)
#pragma unroll
        for (int cp = 0; cp < 2; ++cp) acc[r][cp] = F2(0.f, 0.f);

    const f32x2 one = F2(1.f, 1.f);

#pragma unroll 2
    for (int g = 0; g < 16; ++g) {
        const float4 c4 = *(const float4*)&csh[g * 4];
        float4 bv[4];
#pragma unroll
        for (int c = 0; c < 4; ++c)
            bv[c] = *(const float4*)&Bs[(tx * 4 + c) * 65 + g * 4];
#pragma unroll
        for (int r = 0; r < 4; ++r) {
            const float4 av = *(const float4*)&As[(ty * 4 + r) * 65 + g * 4];
#pragma unroll
            for (int cp = 0; cp < 2; ++cp) {
                const float4 B0 = bv[cp * 2], B1 = bv[cp * 2 + 1];
                f32x2 y0 = F2(B0.x, B1.x) * av.x + one;
                f32x2 y1 = F2(B0.y, B1.y) * av.y + one;
                f32x2 y2 = F2(B0.z, B1.z) * av.z + one;
                f32x2 y3 = F2(B0.w, B1.w) * av.w + one;
                f32x2 y01 = y0 * y1, y23 = y2 * y3;
                f32x2 d = y01 * y23;
                f32x2 n = (y1 * c4.x + y0 * c4.y) * y23 + (y3 * c4.z + y2 * c4.w) * y01;
                acc[r][cp] += n * F2(fast_rcp(d.x), fast_rcp(d.y));
            }
        }
    }

    float* Eb = EP + (long)s * 524288 + (long)b * 65536 + (long)(ti * 64) * 256 + tj * 64;
#pragma unroll
    for (int r = 0; r < 4; ++r) {
        float4 wv = make_float4(acc[r][0].x, acc[r][0].y, acc[r][1].x, acc[r][1].y);
        *(float4*)&Eb[(ty * 4 + r) * 256 + tx * 4] = wv;
    }
}

// ---------------- stage 3: combine 8 partials + softmax over i (axis=1) ----------------
__global__ __launch_bounds__(256) void softmax_kernel(const float* __restrict__ EP,
                                                      float* __restrict__ out) {
    const int b  = blockIdx.x >> 4;
    const int jt = blockIdx.x & 15;
    const int t  = threadIdx.x;
    const int jx = t & 15;
    const int iy = t >> 4;
    const long base = (long)b * 65536 + jt * 16 + jx;

    float v[16];
#pragma unroll
    for (int k = 0; k < 16; ++k) {
        long idx = base + (long)(iy + k * 16) * 256;
        float sum = 0.f;
#pragma unroll
        for (int p = 0; p < 8; ++p) sum += EP[(long)p * 524288 + idx];
        v[k] = -sum;
    }

    float m = v[0];
#pragma unroll
    for (int k = 1; k < 16; ++k) m = fmaxf(m, v[k]);

    __shared__ float red[256];
    red[t] = m;
    __syncthreads();
    if (t < 128) red[t] = fmaxf(red[t], red[t + 128]);
    __syncthreads();
    if (t < 64) red[t] = fmaxf(red[t], red[t + 64]);
    __syncthreads();
    if (t < 32) red[t] = fmaxf(red[t], red[t + 32]);
    __syncthreads();
    if (t < 16) red[t] = fmaxf(red[t], red[t + 16]);
    __syncthreads();
    m = red[jx];
    __syncthreads();

    float ssum = 0.f;
#pragma unroll
    for (int k = 0; k < 16; ++k) {
        v[k] = fast_exp2((v[k] - m) * LOG2E);
        ssum += v[k];
    }
    red[t] = ssum;
    __syncthreads();
    if (t < 128) red[t] += red[t + 128];
    __syncthreads();
    if (t < 64) red[t] += red[t + 64];
    __syncthreads();
    if (t < 32) red[t] += red[t + 32];
    __syncthreads();
    if (t < 16) red[t] += red[t + 16];
    __syncthreads();
    float inv = fast_rcp(red[jx]);

#pragma unroll
    for (int k = 0; k < 16; ++k) {
        long idx = base + (long)(iy + k * 16) * 256;
        out[idx] = v[k] * inv;
    }
}

extern "C" void kernel_launch(void* const* d_in, const int* in_sizes, int n_in,
                              void* d_out, int out_size, void* d_ws, size_t ws_size,
                              hipStream_t stream) {
    const float* inputs  = (const float*)d_in[0];  // (256, 8, 512)
    const float* attn_W  = (const float*)d_in[1];  // (512, 1024)
    const float* attn_b  = (const float*)d_in[2];  // (512,)
    const float* score_W = (const float*)d_in[3];  // (1, 512)
    float* out = (float*)d_out;                    // (8, 256, 256)

    float* ws = (float*)d_ws;
    float* E1 = ws;                                // 1M f32 exp panel
    float* E2 = ws + (1 << 20);                    // 1M f32
    float* EP = ws + (2 << 20);                    // 8 * 512K f32 partials (16 MB)
    ushort* Ap = (ushort*)(ws + (6 << 20));        // 3.146M bf16
    ushort* Bp = Ap + 3145728;                     // 1.573M bf16

    pack_kernel<<<2304, 256, 0, stream>>>(inputs, attn_W, Ap, Bp);
    mfma_gemm<<<256, 256, 0, stream>>>(Ap, Bp, attn_b, E1, E2);
    energy_kernel<<<1024, 256, 0, stream>>>(E1, E2, score_W, EP);
    softmax_kernel<<<128, 256, 0, stream>>>(EP, out);
}

// Round 8
// 67.573 us; speedup vs baseline: 1.3146x; 1.3146x over previous
//
#include <hip/hip_runtime.h>

#define LOG2E 1.4426950408889634f
#define SCALE (2.0f * LOG2E)

__device__ __forceinline__ float fast_exp2(float x) { return __builtin_amdgcn_exp2f(x); }
__device__ __forceinline__ float fast_rcp(float x)  { return __builtin_amdgcn_rcpf(x); }

typedef __attribute__((ext_vector_type(8))) short bf16x8;
typedef __attribute__((ext_vector_type(4))) float f32x4;

// ---------------- stage 0: pack A/B into bf16 hi/lo MFMA fragment panels ----------------
// Logical GEMM: C[m,n] = sum_{kp=0}^{1535} A[m,kp]*B[n,kp]
//   kp segment 0: x_hi*w_hi ; 1: x_lo*w_hi ; 2: x_hi*w_lo   (lo*lo dropped, ~1e-5 rel)
// Panel layout (ushort): [tb][kt(24)][ks(2)][frag(4)][lane(64)][j(8)]
__global__ __launch_bounds__(256) void pack_kernel(const float* __restrict__ inputs,
                                                   const float* __restrict__ attn_W,
                                                   ushort* __restrict__ Ap,
                                                   ushort* __restrict__ Bp) {
    int tid = blockIdx.x * 256 + threadIdx.x;
    const bool isA = tid < 393216;
    int f = isA ? tid : tid - 393216;
    int l  = f & 63;
    int fr = (f >> 6) & 3;
    int ks = (f >> 8) & 1;
    int rem = f >> 9;
    int kt = rem % 24, tb = rem / 24;
    int kp = kt * 64 + ks * 32 + (l >> 4) * 8;
    int seg = kp >> 9, k = kp & 511;
    const float* src;
    bool useLo;
    if (isA) {
        int m = tb * 64 + fr * 16 + (l & 15);
        src = inputs + ((m & 255) * 8 + (m >> 8)) * 512 + k;
        useLo = (seg == 1);
    } else {
        int n = tb * 64 + fr * 16 + (l & 15);
        src = attn_W + (n & 511) * 1024 + (n >> 9) * 512 + k;
        useLo = (seg == 2);
    }
    float4 v0 = *(const float4*)src;
    float4 v1 = *(const float4*)(src + 4);
    float vv[8] = {v0.x, v0.y, v0.z, v0.w, v1.x, v1.y, v1.z, v1.w};
    ushort o[8];
#pragma unroll
    for (int j = 0; j < 8; ++j) {
        unsigned u = __float_as_uint(vv[j]);
        unsigned hi = (u + 0x7FFF + ((u >> 16) & 1)) >> 16;   // RN bf16
        if (useLo) {
            float lo = vv[j] - __uint_as_float(hi << 16);
            unsigned ul = __float_as_uint(lo);
            o[j] = (ushort)((ul + 0x7FFF + ((ul >> 16) & 1)) >> 16);
        } else {
            o[j] = (ushort)hi;
        }
    }
    ushort* dst = (isA ? Ap : Bp) + (long)f * 8;
    *(uint4*)dst = *(const uint4*)o;
}

// ---------------- stage 1: barrier-free direct-fragment MFMA GEMM ----------------
// 1024 independent waves, each owns a 64(m)x32(n) output tile; fragments loaded
// straight from the panels (1KB coalesced per frag), 3-buffer register rotation.
// Panel frag addr: [tb]*98304 + kk*2048 + fr*512 + lane*8   (kk = kt*2+ks, 0..47)
__global__ __launch_bounds__(256) void mfma_gemm(const ushort* __restrict__ Ap,
                                                 const ushort* __restrict__ Bp,
                                                 const float* __restrict__ attn_b,
                                                 float* __restrict__ E1,
                                                 float* __restrict__ E2) {
    // XCD swizzle: blocks sharing an A-panel (8 consecutive) land on one XCD (256=8*32)
    const int lb = (blockIdx.x & 7) * 32 + (blockIdx.x >> 3);
    const int w = (lb << 2) | (threadIdx.x >> 6);   // 0..1023
    const int lane = threadIdx.x & 63;
    const int mt  = w >> 5;                          // 0..31 (64-row A panel)
    const int nt2 = w & 31;                          // 0..31 (32-col half B panel)

    const ushort* pa = Ap + (long)mt * 98304 + lane * 8;
    const ushort* pb = Bp + (long)(nt2 >> 1) * 98304 + (nt2 & 1) * 1024 + lane * 8;

    f32x4 acc[4][2];
#pragma unroll
    for (int i = 0; i < 4; ++i)
#pragma unroll
        for (int j = 0; j < 2; ++j)
            acc[i][j] = (f32x4){0.f, 0.f, 0.f, 0.f};

    bf16x8 bufA[3][4], bufB[3][2];
#define LOADK(kk, s)                                              \
    {                                                             \
        const ushort* qa = pa + (kk) * 2048;                      \
        const ushort* qb = pb + (kk) * 2048;                      \
        bufA[s][0] = *(const bf16x8*)qa;                          \
        bufA[s][1] = *(const bf16x8*)(qa + 512);                  \
        bufA[s][2] = *(const bf16x8*)(qa + 1024);                 \
        bufA[s][3] = *(const bf16x8*)(qa + 1536);                 \
        bufB[s][0] = *(const bf16x8*)qb;                          \
        bufB[s][1] = *(const bf16x8*)(qb + 512);                  \
    }

    LOADK(0, 0);
    LOADK(1, 1);
#pragma unroll 3
    for (int kk = 0; kk < 48; ++kk) {
        const int cur = kk % 3;
        if (kk < 46) {
            const int nxt = (kk + 2) % 3;
            LOADK(kk + 2, nxt);
        }
#pragma unroll
        for (int mf = 0; mf < 4; ++mf)
#pragma unroll
            for (int nn = 0; nn < 2; ++nn)
                acc[mf][nn] = __builtin_amdgcn_mfma_f32_16x16x32_bf16(
                    bufA[cur][mf], bufB[cur][nn], acc[mf][nn], 0, 0, 0);
    }
#undef LOADK

    // epilogue: D col = lane&15 -> n, row = (lane>>4)*4 + r -> m (m89-verified layout)
    const bool isE1 = (nt2 < 16);
    float* dst = isE1 ? E1 : E2;
#pragma unroll
    for (int nn = 0; nn < 2; ++nn) {
        int n = nt2 * 32 + nn * 16 + (lane & 15);
        int o = n & 511;
        float bias = isE1 ? attn_b[o] : 0.0f;
#pragma unroll
        for (int mf = 0; mf < 4; ++mf) {
            int ml = mt * 64 + mf * 16 + ((lane >> 4) << 2);   // global m, +r below
            int bb = ml >> 8, l = ml & 255;
            long rowoff = ((long)(bb * 8 + (l >> 5)) * 512 + o) * 32 + (l & 31);
#pragma unroll
            for (int r = 0; r < 4; ++r)
                dst[rowoff + r] = fast_exp2(SCALE * (acc[mf][nn][r] + bias));
        }
    }
}

// ---------------- stage 2: partial energies (R4-exact) ----------------
// EP[s][b][i][j] = sum_{o in chunk s (128)} c_o * rcp(1 + E1[b,i,o]*E2[b,j,o])
__global__ __launch_bounds__(256) void energy_kernel(const float* __restrict__ E1,
                                                     const float* __restrict__ E2,
                                                     const float* __restrict__ sW,
                                                     float* __restrict__ EP) {
    const int bid = blockIdx.x;       // 2048 = 8 b * 8 ti * 8 tj * 4 s
    const int s  = bid & 3;
    const int tj = (bid >> 2) & 7;
    const int ti = (bid >> 5) & 7;
    const int b  = bid >> 8;
    __shared__ float p1s[64 * 32];
    __shared__ float p2s[64 * 32];
    __shared__ float csh[128];

    const int t = threadIdx.x;
    const int tx = t & 15, ty = t >> 4;

    if (t < 128) csh[t] = 2.0f * sW[s * 128 + t];

    const float* p1base = E1 + ((long)(b * 8 + ti) * 512 + s * 128) * 32;
    const float* p2base = E2 + ((long)(b * 8 + tj) * 512 + s * 128) * 32;

    float acc00 = 0.f, acc01 = 0.f, acc10 = 0.f, acc11 = 0.f;

    for (int c0 = 0; c0 < 128; c0 += 64) {
        __syncthreads();
        const float4* s1 = (const float4*)(p1base + c0 * 32);
        const float4* s2 = (const float4*)(p2base + c0 * 32);
        float4* d1 = (float4*)p1s;
        float4* d2 = (float4*)p2s;
        d1[t] = s1[t];  d1[256 + t] = s1[256 + t];
        d2[t] = s2[t];  d2[256 + t] = s2[256 + t];
        __syncthreads();
#pragma unroll 8
        for (int hh = 0; hh < 64; ++hh) {
            float c = csh[c0 + hh];
            float2 a  = *(const float2*)&p1s[hh * 32 + ty * 2];
            float2 bj = *(const float2*)&p2s[hh * 32 + tx * 2];
            acc00 = fmaf(c, fast_rcp(fmaf(a.x, bj.x, 1.0f)), acc00);
            acc01 = fmaf(c, fast_rcp(fmaf(a.x, bj.y, 1.0f)), acc01);
            acc10 = fmaf(c, fast_rcp(fmaf(a.y, bj.x, 1.0f)), acc10);
            acc11 = fmaf(c, fast_rcp(fmaf(a.y, bj.y, 1.0f)), acc11);
        }
    }

    float* Eb = EP + (long)s * 524288 + (long)b * 65536 + (ti * 32) * 256 + tj * 32;
    *(float2*)&Eb[(ty * 2 + 0) * 256 + tx * 2] = make_float2(acc00, acc01);
    *(float2*)&Eb[(ty * 2 + 1) * 256 + tx * 2] = make_float2(acc10, acc11);
}

// ---------------- stage 3: combine partials + softmax over i (axis=1) ----------------
__global__ __launch_bounds__(256) void softmax_kernel(const float* __restrict__ P0,
                                                      const float* __restrict__ P1,
                                                      const float* __restrict__ P2,
                                                      const float* __restrict__ P3,
                                                      float* __restrict__ out) {
    const int b  = blockIdx.x >> 4;
    const int jt = blockIdx.x & 15;
    const int t  = threadIdx.x;
    const int jx = t & 15;
    const int iy = t >> 4;
    const long base = (long)b * 65536 + jt * 16 + jx;

    float v[16];
#pragma unroll
    for (int k = 0; k < 16; ++k) {
        long idx = base + (long)(iy + k * 16) * 256;
        v[k] = -(P0[idx] + P1[idx] + P2[idx] + P3[idx]);
    }

    float m = v[0];
#pragma unroll
    for (int k = 1; k < 16; ++k) m = fmaxf(m, v[k]);

    __shared__ float red[256];
    red[t] = m;
    __syncthreads();
    if (t < 128) red[t] = fmaxf(red[t], red[t + 128]);
    __syncthreads();
    if (t < 64) red[t] = fmaxf(red[t], red[t + 64]);
    __syncthreads();
    if (t < 32) red[t] = fmaxf(red[t], red[t + 32]);
    __syncthreads();
    if (t < 16) red[t] = fmaxf(red[t], red[t + 16]);
    __syncthreads();
    m = red[jx];
    __syncthreads();

    float ssum = 0.f;
#pragma unroll
    for (int k = 0; k < 16; ++k) {
        v[k] = fast_exp2((v[k] - m) * LOG2E);
        ssum += v[k];
    }
    red[t] = ssum;
    __syncthreads();
    if (t < 128) red[t] += red[t + 128];
    __syncthreads();
    if (t < 64) red[t] += red[t + 64];
    __syncthreads();
    if (t < 32) red[t] += red[t + 32];
    __syncthreads();
    if (t < 16) red[t] += red[t + 16];
    __syncthreads();
    float inv = fast_rcp(red[jx]);

#pragma unroll
    for (int k = 0; k < 16; ++k) {
        long idx = base + (long)(iy + k * 16) * 256;
        out[idx] = v[k] * inv;
    }
}

extern "C" void kernel_launch(void* const* d_in, const int* in_sizes, int n_in,
                              void* d_out, int out_size, void* d_ws, size_t ws_size,
                              hipStream_t stream) {
    const float* inputs  = (const float*)d_in[0];  // (256, 8, 512)
    const float* attn_W  = (const float*)d_in[1];  // (512, 1024)
    const float* attn_b  = (const float*)d_in[2];  // (512,)
    const float* score_W = (const float*)d_in[3];  // (1, 512)
    float* out = (float*)d_out;                    // (8, 256, 256)

    float* ws = (float*)d_ws;
    float* E1 = ws;                                // 1M f32 exp panel
    float* E2 = ws + (1 << 20);                    // 1M f32
    float* EP = ws + (2 << 20);                    // 4 * 512K f32 partials (8 MB)
    ushort* Ap = (ushort*)(ws + (4 << 20));        // 3.146M bf16
    ushort* Bp = Ap + 3145728;                     // 1.573M bf16

    pack_kernel<<<2304, 256, 0, stream>>>(inputs, attn_W, Ap, Bp);
    mfma_gemm<<<256, 256, 0, stream>>>(Ap, Bp, attn_b, E1, E2);
    energy_kernel<<<2048, 256, 0, stream>>>(E1, E2, score_W, EP);
    softmax_kernel<<<128, 256, 0, stream>>>(EP, EP + 524288, EP + 2 * 524288,
                                            EP + 3 * 524288, out);
}